// Round 6
// baseline (94.128 us; speedup 1.0000x reference)
//
#include <hip/hip_runtime.h>

#define NB 2
#define NG 1024
#define HEIGHT 128
#define WIDTH 128
#define HW (HEIGHT * WIDTH)
#define E10 4.5399931e-05f                 // exp(-10)
#define PW 134                             // padded width (3px apron)
#define PPLANE (PW * PW)                   // padded plane = 17956
#define PFX_STRIDE 8200                    // 1025 * 8 floats per batch

// ws layout (float indices)
#define REC_S 0                            // sorted records: 2048*16
#define P_ENT 32768                        // 32 entropy partials
#define P_L1D 32800                        // 512 depth-l1 partials
#define P_SSS 33312                        // 192 ssim partials
#define P_SSL 33504                        // 192 rgb-l1 partials
#define CNT_I 33696                        // int: finished-ssim-block counter
#define PFX   33700                        // background prefix: 2*1025*8 = 16400
#define RGBOF 50100                        // padded rgb: 6*134*134 = 107736
// record: [0]px [1]py [2]hx [3]hy [4]i00 [5]i01 [6]i11 [7]op [8]c0 [9]c1 [10]c2 [11]z [12..15] unused
// prefix P_k (stride 8): [0]Tt [1]Ur [2]Ug [3]Ub [4]Ud  (background affine of ranks [0,k))

__device__ inline float blk_reduce(float v, float* sh) {
    for (int off = 32; off > 0; off >>= 1) v += __shfl_down(v, off, 64);
    int lane = threadIdx.x & 63;
    int w = threadIdx.x >> 6;
    __syncthreads();
    if (lane == 0) sh[w] = v;
    __syncthreads();
    float s = 0.f;
    if (threadIdx.x == 0) {
        int nw = (blockDim.x + 63) >> 6;
        for (int i = 0; i < nw; i++) s += sh[i];
    }
    return s;  // valid on thread 0 only
}

// ========== K1: fused pre + rank (32 blocks x 256) ==========================
__global__ __launch_bounds__(256) void k_prerank(const float* __restrict__ g,
                                                 const float* __restrict__ intr,
                                                 float* __restrict__ ws) {
    __shared__ __align__(16) unsigned long long zkey[NG];
    __shared__ int sp[256];
    int bid = blockIdx.x;        // 0..31
    int b = bid >> 4;            // batch
    int grp = bid & 15;          // which 64 gaussians
    int tid = threadIdx.x;

    // stage all 1024 sort keys of this batch
#pragma unroll
    for (int q = 0; q < 4; q++) {
        int j = tid + q * 256;
        float z = fmaxf(g[(size_t)((b << 10) + j) * 38 + 2], 1e-4f);
        zkey[j] = ((unsigned long long)__float_as_uint(z) << 10) | (unsigned)j;
    }
    __syncthreads();

    int il = (grp << 6) + (tid & 63);
    int jq = tid >> 6;           // j-quarter (wave-uniform)
    unsigned long long ki = zkey[il];
    int rank = 0;
    int j0 = jq << 8;
#pragma unroll 4
    for (int j = j0; j < j0 + 256; j += 2) {
        ulonglong2 kk = *(const ulonglong2*)(zkey + j);  // uniform addr -> broadcast
        rank += (kk.x < ki);
        rank += (kk.y < ki);
    }
    sp[tid] = rank;
    __syncthreads();

    if (tid < 64) {
        int r = sp[tid] + sp[tid + 64] + sp[tid + 128] + sp[tid + 192];
        int idx = (b << 10) + il;
        const float* row = g + (size_t)idx * 38;
        float mx = row[0], my = row[1], mz = row[2];
        float sx = row[3], sy = row[4], sz = row[5];
        float qw = row[6], qx = row[7], qy = row[8], qz = row[9];
        float op = row[10];
        float sh0 = row[11], sh1 = row[12], sh2 = row[13];
        float fx = intr[b * 9 + 0], fy = intr[b * 9 + 4];
        float cx = intr[b * 9 + 2], cy = intr[b * 9 + 5];

        float z = fmaxf(mz, 1e-4f);
        float px = fx * mx / z + cx;
        float py = fy * my / z + cy;

        float r00 = 1.f - 2.f * (qy * qy + qz * qz), r01 = 2.f * (qx * qy - qw * qz), r02 = 2.f * (qx * qz + qw * qy);
        float r10 = 2.f * (qx * qy + qw * qz), r11 = 1.f - 2.f * (qx * qx + qz * qz), r12 = 2.f * (qy * qz - qw * qx);
        float r20 = 2.f * (qx * qz - qw * qy), r21 = 2.f * (qy * qz + qw * qx), r22 = 1.f - 2.f * (qx * qx + qy * qy);
        float a00 = r00 * sx, a01 = r01 * sy, a02 = r02 * sz;
        float a10 = r10 * sx, a11 = r11 * sy, a12 = r12 * sz;
        float a20 = r20 * sx, a21 = r21 * sy, a22 = r22 * sz;
        float m00 = a00 * a00 + a01 * a01 + a02 * a02;
        float m01 = a00 * a10 + a01 * a11 + a02 * a12;
        float m02 = a00 * a20 + a01 * a21 + a02 * a22;
        float m11 = a10 * a10 + a11 * a11 + a12 * a12;
        float m12 = a10 * a20 + a11 * a21 + a12 * a22;
        float m22 = a20 * a20 + a21 * a21 + a22 * a22;

        float zc = fmaxf(mz, 1e-6f);
        float aJ = fx / zc, bJ = -fx * mx / (zc * zc);
        float cJ = fy / zc, dJ = -fy * my / (zc * zc);
        float c00 = aJ * aJ * m00 + 2.f * aJ * bJ * m02 + bJ * bJ * m22 + 0.3f;
        float c01 = cJ * (aJ * m01 + bJ * m12) + dJ * (aJ * m02 + bJ * m22);
        float c11 = cJ * cJ * m11 + 2.f * cJ * dJ * m12 + dJ * dJ * m22 + 0.3f;
        float det = fmaxf(c00 * c11 - c01 * c01, 1e-8f);
        float i00 = c11 / det;
        float i11 = c00 / det;
        float i01 = -c01 / det;

        const float C0c = 0.28209479177387814f;
        float col0 = fminf(fmaxf(sh0 * C0c + 0.5f, 0.f), 1.f);
        float col1 = fminf(fmaxf(sh1 * C0c + 0.5f, 0.f), 1.f);
        float col2 = fminf(fmaxf(sh2 * C0c + 0.5f, 0.f), 1.f);

        float hx = sqrtf(20.f * c00);      // power>-10 ellipse bbox half-extents
        float hy = sqrtf(20.f * c11);

        float* rec = ws + REC_S + (size_t)((b << 10) + r) * 16;
        ((float4*)rec)[0] = make_float4(px, py, hx, hy);
        ((float4*)rec)[1] = make_float4(i00, i01, i11, op);
        ((float4*)rec)[2] = make_float4(col0, col1, col2, z);

        float o = fminf(fmaxf(op, 1e-6f), 1.f - 1e-6f);
        float ent = -(o * logf(o) + (1.f - o) * logf(1.f - o));
        for (int off = 32; off > 0; off >>= 1) ent += __shfl_down(ent, off, 64);
        if (tid == 0) ws[P_ENT + bid] = ent;
    }
    // zero padded rgb region (interior overwritten later by k_render)
    for (int i = bid * 256 + tid; i < 6 * PPLANE; i += 32 * 256)
        ws[RGBOF + i] = 0.f;
    if (bid == 0 && tid == 0) ((int*)ws)[CNT_I] = 0;  // for K4 last-block pattern
}

// ========== K2: background prefix scan (NB blocks x 1024) ===================
// P_k = background affine of z-ranks [0,k): (T,C) -> (T*Tt_k, C + T*U_k)
__global__ __launch_bounds__(1024) void k_scan(float* __restrict__ ws) {
    __shared__ float sagg[16 * 5];
    int b = blockIdx.x;
    int tid = threadIdx.x;
    int lane = tid & 63;
    int wv = tid >> 6;
    const float* rec = ws + REC_S + (size_t)((b << 10) + tid) * 16;
    float4 q1 = ((const float4*)rec)[1];   // i00 i01 i11 op
    float4 q2 = ((const float4*)rec)[2];   // c0 c1 c2 z
    float a10 = E10 * q1.w;
    float t = 1.f - a10;
    float ur = a10 * q2.x, ug = a10 * q2.y, ub = a10 * q2.z, ud = a10 * q2.w;
#pragma unroll
    for (int off = 1; off < 64; off <<= 1) {
        float pt = __shfl_up(t, off, 64);
        float pr = __shfl_up(ur, off, 64);
        float pg = __shfl_up(ug, off, 64);
        float pb = __shfl_up(ub, off, 64);
        float pd = __shfl_up(ud, off, 64);
        if (lane >= off) {
            ur = pr + pt * ur; ug = pg + pt * ug;
            ub = pb + pt * ub; ud = pd + pt * ud;
            t = pt * t;
        }
    }
    if (lane == 63) {
        sagg[wv * 5 + 0] = t;  sagg[wv * 5 + 1] = ur; sagg[wv * 5 + 2] = ug;
        sagg[wv * 5 + 3] = ub; sagg[wv * 5 + 4] = ud;
    }
    __syncthreads();
    // wave 0 lanes 0..15: exclusive affine scan over the 16 wave aggregates
    if (tid < 16) {
        float at = sagg[tid * 5 + 0], ar = sagg[tid * 5 + 1], ag = sagg[tid * 5 + 2];
        float ab = sagg[tid * 5 + 3], ad = sagg[tid * 5 + 4];
#pragma unroll
        for (int off = 1; off < 16; off <<= 1) {
            float pt = __shfl_up(at, off, 16);
            float pr = __shfl_up(ar, off, 16);
            float pg = __shfl_up(ag, off, 16);
            float pb = __shfl_up(ab, off, 16);
            float pd = __shfl_up(ad, off, 16);
            if (tid >= off) {
                ar = pr + pt * ar; ag = pg + pt * ag;
                ab = pb + pt * ab; ad = pd + pt * ad;
                at = pt * at;
            }
        }
        float eat = __shfl_up(at, 1, 16);
        float ear = __shfl_up(ar, 1, 16);
        float eag = __shfl_up(ag, 1, 16);
        float eab = __shfl_up(ab, 1, 16);
        float ead = __shfl_up(ad, 1, 16);
        if (tid == 0) { eat = 1.f; ear = 0.f; eag = 0.f; eab = 0.f; ead = 0.f; }
        sagg[tid * 5 + 0] = eat; sagg[tid * 5 + 1] = ear; sagg[tid * 5 + 2] = eag;
        sagg[tid * 5 + 3] = eab; sagg[tid * 5 + 4] = ead;
    }
    __syncthreads();
    // compose: (exclusive aggregate of my wave) then (my in-wave inclusive)
    float Pt = sagg[wv * 5 + 0], Pur = sagg[wv * 5 + 1], Pug = sagg[wv * 5 + 2];
    float Pub = sagg[wv * 5 + 3], Pud = sagg[wv * 5 + 4];
    float* P = ws + PFX + (size_t)b * PFX_STRIDE;
    ((float4*)(P + (size_t)(tid + 1) * 8))[0] =
        make_float4(Pt * t, Pur + Pt * ur, Pug + Pt * ug, Pub + Pt * ub);
    P[(size_t)(tid + 1) * 8 + 4] = Pud + Pt * ud;
    if (tid == 0) {
        ((float4*)P)[0] = make_float4(1.f, 0.f, 0.f, 0.f);
        P[4] = 0.f;
    }
}

// ========== K3: bin + render (512 blocks x 1024) ============================
// Thin per-block work: bbox-only load + ballot bin + coalesced LDS copy of the
// precomputed prefix table, then the verified prefix-quotient render.
__global__ __launch_bounds__(1024, 8) void k_render(const float* __restrict__ tgt_d,
                                                    float* __restrict__ ws) {
    __shared__ float4 sPa[NG + 1];         // prefix: Tt, Ur, Ug, Ub
    __shared__ float sPud[NG + 1];         // prefix: Ud
    __shared__ unsigned short slist[NG];
    __shared__ int swcnt[16];
    __shared__ float comb[5][1024];

    int tid = threadIdx.x;
    int lane = tid & 63;
    int wv = tid >> 6;
    int blk = blockIdx.x;  // 512 tiles
    int b = blk >> 8;
    int tt = blk & 255;
    int x0 = (tt & 15) * 8, y0 = (tt >> 4) * 8;
    int x = x0 + (lane & 7), y = y0 + (lane >> 3);
    float xf = (float)x, yf = (float)y;
    float x0f = (float)x0, x1f = x0f + 7.f;
    float y0f = (float)y0, y1f = y0f + 7.f;

    const float* recs = ws + REC_S + (size_t)(b << 10) * 16;

    // ---- bin: bbox-only load, ballot-compact overlap list ----
    float4 q0 = ((const float4*)(recs + (size_t)tid * 16))[0];  // px py hx hy
    bool ov = (q0.x + q0.z >= x0f) && (q0.x - q0.z <= x1f) &&
              (q0.y + q0.w >= y0f) && (q0.y - q0.w <= y1f);
    unsigned long long mask = __ballot(ov);
    int loff = __popcll(mask & ((1ull << lane) - 1ull));
    if (lane == 0) swcnt[wv] = (int)__popcll(mask);

    // ---- stage prefix table (coalesced global -> LDS copy) ----
    {
        const float* P = ws + PFX + (size_t)b * PFX_STRIDE;
        for (int i = tid; i <= NG; i += 1024) {
            const float* Pe = P + (size_t)i * 8;
            sPa[i] = *(const float4*)Pe;
            sPud[i] = Pe[4];
        }
    }
    __syncthreads();

    // bin offsets + total
    int woff = 0, cnt = 0;
#pragma unroll
    for (int i = 0; i < 16; i++) {
        int ci = swcnt[i];
        woff += (i < wv) ? ci : 0;
        cnt += ci;
    }
    if (ov) slist[woff + loff] = (unsigned short)tid;
    __syncthreads();

    // ---- render: 16 waves split the tile list into contiguous z-chunks ----
    int m = (cnt + 15) >> 4;
    int p0 = wv * m; if (p0 > cnt) p0 = cnt;
    int p1 = p0 + m; if (p1 > cnt) p1 = cnt;
    int s0 = (p0 == 0) ? 0 : (int)slist[p0 - 1] + 1;

    float4 Pa = sPa[s0];
    float Pud = sPud[s0];
    float inv0 = 1.f / Pa.x;               // 1/Tt_s0 (in [1, 1.05])
    float Pur2 = Pa.y, Pug2 = Pa.z, Pub2 = Pa.w;

    float tau = 1.f, cr = 0.f, cgn = 0.f, cb = 0.f, cd = 0.f;
    int r = (p0 < p1) ? (int)slist[p0] : 0;
    for (int p = p0; p < p1; p++) {
        int rn = (p + 1 < p1) ? (int)slist[p + 1] : 0;   // 1-deep prefetch
        float4 Qa = sPa[r];
        float Qud = sPud[r];
        const float* rp = recs + (size_t)r * 16;
        float4 g0 = ((const float4*)rp)[0];  // px py hx hy
        float4 g1 = ((const float4*)rp)[1];  // i00 i01 i11 op
        float4 g2 = ((const float4*)rp)[2];  // c0 c1 c2 z
        float kap = tau * inv0;
        // background run [prev, r)
        cr += kap * (Qa.y - Pur2);
        cgn += kap * (Qa.z - Pug2);
        cb += kap * (Qa.w - Pub2);
        cd += kap * (Qud - Pud);
        // item r (exact: clamp covers out-of-ellipse pixels)
        float dx = xf - g0.x, dy = yf - g0.y;
        float q = g1.x * dx * dx + 2.f * g1.y * dx * dy + g1.z * dy * dy;
        float pw = fminf(fmaxf(-0.5f * q, -10.f), 0.f);
        float a = fminf(__expf(pw) * g1.w, 0.99f);
        float w = kap * Qa.x * a;
        cr += w * g2.x; cgn += w * g2.y; cb += w * g2.z; cd += w * g2.w;
        float a10i = E10 * g1.w;
        tau *= (1.f - a) * (1.f + a10i * (1.f + a10i));  // /(1-a10) to 2nd order
        // advance prefix boundary to r+1 in-register
        float s = Qa.x * a10i;
        Pur2 = Qa.y + s * g2.x;
        Pug2 = Qa.z + s * g2.y;
        Pub2 = Qa.w + s * g2.z;
        Pud = Qud + s * g2.w;
        r = rn;
    }
    int e0 = (wv == 15) ? NG : ((p1 == 0) ? 0 : (int)slist[p1 - 1] + 1);
    float4 Ea = sPa[e0];
    float Eud = sPud[e0];
    float kapf = tau * inv0;
    cr += kapf * (Ea.y - Pur2);
    cgn += kapf * (Ea.z - Pug2);
    cb += kapf * (Ea.w - Pub2);
    cd += kapf * (Eud - Pud);
    float T = tau * Ea.x * inv0;

    comb[0][tid] = T;
    comb[1][tid] = cr;
    comb[2][tid] = cgn;
    comb[3][tid] = cb;
    comb[4][tid] = cd;
    __syncthreads();

    if (tid < 64) {
        float T0 = comb[0][tid], r0 = comb[1][tid], g0 = comb[2][tid];
        float b0 = comb[3][tid], d0 = comb[4][tid];
#pragma unroll
        for (int sgi = 1; sgi < 16; sgi++) {
            int j = sgi * 64 + tid;
            r0 += T0 * comb[1][j];
            g0 += T0 * comb[2][j];
            b0 += T0 * comb[3][j];
            d0 += T0 * comb[4][j];
            T0 *= comb[0][j];
        }
        r0 = fminf(fmaxf(r0, 0.f), 1.f);
        g0 = fminf(fmaxf(g0, 0.f), 1.f);
        b0 = fminf(fmaxf(b0, 0.f), 1.f);
        float* rgb = ws + RGBOF;
        int pofs = (y + 3) * PW + (x + 3);
        rgb[(b * 3 + 0) * PPLANE + pofs] = r0;
        rgb[(b * 3 + 1) * PPLANE + pofs] = g0;
        rgb[(b * 3 + 2) * PPLANE + pofs] = b0;
        float l1d = fabsf(d0 - tgt_d[(b * HEIGHT + y) * WIDTH + x]);
        for (int off = 32; off > 0; off >>= 1) l1d += __shfl_down(l1d, off, 64);
        if (tid == 0) ws[P_L1D + blk] = l1d;
    }
}

// ========== K4: SSIM + rgb L1 + fused final reduce (192 blocks x 256) =======
__global__ __launch_bounds__(256) void k_ssim_final(const float* __restrict__ tgt_rgb,
                                                    float* __restrict__ ws,
                                                    float* __restrict__ out) {
    __shared__ float s1[14 * 70];
    __shared__ float s2[14 * 70];
    __shared__ float sh[8];
    __shared__ int sflag;
    int bid = blockIdx.x;                  // 0..191
    int tid = threadIdx.x;
    int p = bid >> 5;                      // plane 0..5 (= b*3+ch)
    int sy = (bid >> 1) & 15;              // row strip
    int hx2 = bid & 1;                     // col half
    int y0 = sy * 8, x0 = hx2 * 64;

    // stage: img1 from padded ws (no bounds checks), tgt with zero-fill
    const float* img1p = ws + RGBOF + (size_t)p * PPLANE;
    const float* tgtp = tgt_rgb + (size_t)p * HW;
    for (int i = tid; i < 14 * 70; i += 256) {
        int r = i / 70, c = i - r * 70;
        s1[i] = img1p[(y0 + r) * PW + (x0 + c)];
        int yy = y0 + r - 3, xx = x0 + c - 3;
        float v = 0.f;
        if (yy >= 0 && yy < HEIGHT && xx >= 0 && xx < WIDTH)
            v = tgtp[yy * WIDTH + xx];
        s2[i] = v;
    }
    __syncthreads();

    float gg[7];
    float gs = 0.f;
#pragma unroll
    for (int i = 0; i < 7; i++) {
        float c = (float)(i - 3);
        gg[i] = __expf(-c * c / 4.5f);
        gs += gg[i];
    }
#pragma unroll
    for (int i = 0; i < 7; i++) gg[i] /= gs;

    int row = tid >> 5;                    // 0..7
    int colb = (tid & 31) * 2;             // 0..62
    float ssim_acc = 0.f, l1_acc = 0.f;
#pragma unroll
    for (int j = 0; j < 2; j++) {
        int c = colb + j;
        float mu1 = 0.f, mu2 = 0.f, s11 = 0.f, s22 = 0.f, s12 = 0.f;
#pragma unroll
        for (int dy = 0; dy < 7; dy++) {
            int rb = (row + dy) * 70 + c;
#pragma unroll
            for (int dx = 0; dx < 7; dx++) {
                float w = gg[dy] * gg[dx];
                float i1 = s1[rb + dx];
                float i2 = s2[rb + dx];
                mu1 += w * i1;
                mu2 += w * i2;
                s11 += w * i1 * i1;
                s22 += w * i2 * i2;
                s12 += w * i1 * i2;
            }
        }
        float v1 = s11 - mu1 * mu1;
        float v2 = s22 - mu2 * mu2;
        float cv = s12 - mu1 * mu2;
        const float C1 = 1e-4f, C2 = 9e-4f;
        ssim_acc += ((2.f * mu1 * mu2 + C1) * (2.f * cv + C2)) /
                    ((mu1 * mu1 + mu2 * mu2 + C1) * (v1 + v2 + C2));
        int ctr = (row + 3) * 70 + c + 3;
        l1_acc += fabsf(s1[ctr] - s2[ctr]);
    }

    float s_ssim = blk_reduce(ssim_acc, sh);
    float s_l1 = blk_reduce(l1_acc, sh);

    // last-block-done: partials -> fence -> counter; final block reduces all
    if (tid == 0) {
        ws[P_SSS + bid] = s_ssim;
        ws[P_SSL + bid] = s_l1;
        __threadfence();
        int old = atomicAdd((int*)ws + CNT_I, 1);
        sflag = (old == 191) ? 1 : 0;
    }
    __syncthreads();
    if (sflag) {
        __threadfence();                   // acquire: see all blocks' partials
        float d = 0.f, ss = 0.f, sl = 0.f, e = 0.f;
        for (int i = tid; i < 512; i += 256) d += ws[P_L1D + i];
        if (tid < 192) { ss = ws[P_SSS + tid]; sl = ws[P_SSL + tid]; }
        if (tid < 32) e = ws[P_ENT + tid];
        float rd_ = blk_reduce(d, sh);
        float rss = blk_reduce(ss, sh);
        float rsl = blk_reduce(sl, sh);
        float re = blk_reduce(e, sh);
        if (tid == 0) {
            float l1r = rsl / (float)(NB * 3 * HW);
            float ssimv = rss / (float)(NB * 3 * HW);
            float l1d = rd_ / (float)(NB * HW);
            float opa = re / (float)(NB * NG);
            out[0] = 0.8f * l1r + 0.2f * (1.f - ssimv) + 0.5f * l1d + 0.01f * opa;
        }
    }
}

extern "C" void kernel_launch(void* const* d_in, const int* in_sizes, int n_in,
                              void* d_out, int out_size, void* d_ws, size_t ws_size,
                              hipStream_t stream) {
    const float* g = (const float*)d_in[0];
    const float* intr = (const float*)d_in[1];
    const float* trgb = (const float*)d_in[2];
    const float* tdep = (const float*)d_in[3];
    float* ws = (float*)d_ws;
    float* out = (float*)d_out;

    hipLaunchKernelGGL(k_prerank, dim3(32), dim3(256), 0, stream, g, intr, ws);
    hipLaunchKernelGGL(k_scan, dim3(NB), dim3(1024), 0, stream, ws);
    hipLaunchKernelGGL(k_render, dim3(NB * 256), dim3(1024), 0, stream, tdep, ws);
    hipLaunchKernelGGL(k_ssim_final, dim3(192), dim3(256), 0, stream, trgb, ws, out);
}